// Round 14
// baseline (165.272 us; speedup 1.0000x reference)
//
#include <hip/hip_runtime.h>

// Conv2d 3x3 pad1 stride1, x[1,256,224,224] f32, w[256,256,3,3] f32 -> out[256,224,224] f32
// Implicit GEMM: M=256 (co), N=50176 (h*224+w), K=2304 (tap-major: k = (dh*3+dw)*256 + ci)
// R20: R19 corrected. R19's NaN: B-staging was cut to 128 rows while BN=224 reads rows
//      up to 223 (unstaged LDS). Fix: B staged at 256 rows/buffer. To keep 2 blocks/CU
//      (the anti-phase mechanism: two barrier-independent blocks per CU cover each
//      other's ~550ns/kappa stall), drop to BK=32 with 3 buffers: A 3x4096 + B 3x8192
//      = 72KB <= 80KB -> __launch_bounds__(256,2). Counted ladder, 6 loads/thread/iter:
//      iter kt stages kt+2 (WAR: buf (kt+2)%3 last read at kt-1, sealed by its barrier);
//      vmcnt(6) retires kt+1 (12->6 outstanding, never 0 till tail); 1 barrier/iter.
//      Swizzle verbatim (proven conflicts=0); ascending-k accumulation (absmax 0.0625).
//      B over-stage rows 224-255: sources spill <=9K shorts into ap region (valid
//      memory); land in LDS rows never read.

#define H 224
#define W 224
#define NPOS (H*W)          // 50176
#define CI 256
#define CO 256
#define KDIM 2304
#define HP 226              // padded
#define XP_ELEMS (HP*HP*CI) // 13,075,456 shorts
#define AP_ELEMS (CO*KDIM)  // 589,824 shorts
#define BN 224              // N-tile: 50176/224 = 224 -> grid (224, 2)

typedef __bf16 bf16x8 __attribute__((ext_vector_type(8)));
typedef float f32x4 __attribute__((ext_vector_type(4)));
typedef unsigned short u16x4 __attribute__((ext_vector_type(4)));
typedef unsigned short u16x8 __attribute__((ext_vector_type(8)));

__device__ __forceinline__ unsigned short f2bf(float f) {
    unsigned int u = __float_as_uint(f);
    u += 0x7fff + ((u >> 16) & 1);   // round-to-nearest-even
    return (unsigned short)(u >> 16);
}

__device__ __forceinline__ void load_lds16(const unsigned short* g, unsigned short* l) {
    __builtin_amdgcn_global_load_lds(
        (const __attribute__((address_space(1))) void*)g,
        (__attribute__((address_space(3))) void*)l,
        16, 0, 0);
}

// ---- fused prep (unchanged from R8): xtrans + weight transform + border zero ----
#define XT_BLOCKS 3136      // 784 * 4
#define WT_BLOCKS 256
#define BORDER_V8 28800     // 230,400 shorts / 8
#define ROW_V8 7232         // 226*256/8
__global__ void prep_kernel(const float* __restrict__ x, const float* __restrict__ w,
                            unsigned short* __restrict__ ap, unsigned short* __restrict__ xp) {
    __shared__ unsigned short smem[64 * 68];
    const int bx = blockIdx.x;
    const int t = threadIdx.x;

    if (bx < XT_BLOCKS) {
        const unsigned int pBase = (unsigned int)(bx % 784) * 64;
        const unsigned int ciBase = (unsigned int)(bx / 784) * 64;
        {
            const int p4 = (t & 15) * 4;
            const int c0 = t >> 4;               // 0..15
#pragma unroll
            for (int i = 0; i < 4; ++i) {
                const int ci_l = c0 + i * 16;
                const f32x4 v = *(const f32x4*)&x[(ciBase + ci_l) * NPOS + pBase + p4];
                u16x4 s;
                s[0] = f2bf(v[0]); s[1] = f2bf(v[1]); s[2] = f2bf(v[2]); s[3] = f2bf(v[3]);
                *(u16x4*)&smem[ci_l * 68 + p4] = s;
            }
        }
        __syncthreads();
        {
            const int ci0 = (t & 7) * 8;
            const int pr = t >> 3;               // 0..31
#pragma unroll
            for (int j = 0; j < 2; ++j) {
                const int p_l = pr + j * 32;
                const unsigned int p = pBase + p_l;
                const unsigned int hi = p / W, wi = p - hi * W;
                u16x8 v;
#pragma unroll
                for (int k = 0; k < 8; ++k) v[k] = smem[(ci0 + k) * 68 + p_l];
                *(u16x8*)&xp[((hi + 1) * HP + (wi + 1)) * CI + ciBase + ci0] = v;
            }
        }
    } else if (bx < XT_BLOCKS + WT_BLOCKS) {
        const int co = bx - XT_BLOCKS;
        const float* wc = w + co * KDIM;
#pragma unroll
        for (int i = 0; i < 9; ++i)
            smem[i * 256 + t] = f2bf(wc[i * 256 + t]);
        __syncthreads();
        unsigned short* apc = ap + co * KDIM;
#pragma unroll
        for (int tap = 0; tap < 9; ++tap)
            apc[tap * 256 + t] = smem[t * 9 + tap];
    } else {
        const int idx = (bx - XT_BLOCKS - WT_BLOCKS) * 256 + t;
        if (idx < BORDER_V8) {
            unsigned short* p;
            if (idx < 2 * ROW_V8) {
                const int r = idx / ROW_V8;
                const int off = idx - r * ROW_V8;
                p = xp + r * (225 * HP * CI) + off * 8;
            } else {
                const int i2 = idx - 2 * ROW_V8;
                const int seg = i2 >> 5;
                const int o = i2 & 31;
                const int hp = 1 + (seg >> 1);
                const int wp = (seg & 1) * 225;
                p = xp + (hp * HP + wp) * CI + o * 8;
            }
            *(u16x8*)p = (u16x8){0, 0, 0, 0, 0, 0, 0, 0};
        }
    }
}

// ---- implicit GEMM, 128x224 tile, BK=32, 4 waves (2Mx2N), wave-tile 64x112 ----
// LDS (shorts): A buffers 0..2 at buf*4096 (128 rows x 32); B buffers at
//   12288 + buf*8192 (256 rows staged, rows 224-255 never read). Total 36864 = 72KB.
// Slot s of row r holds chunk s ^ ((r&15)>>1 & 3); source pre-swizzle
//   c4 = (l&3)^((l>>3)&3); read slot quad^((ln15>>1)&3). Proven 0-conflict.
// Per iter kt (K=32): RD_MAIN (af0-1, bf0-6: 9 ds); stageA(kt+2) [2]; 14 MFMA;
//   RD_TAILA (af2-3); stageB(kt+2) [4]; 14 MFMA; vmcnt(6); barrier.
// Ladder: outstanding before wait = kt+1's 6 + kt+2's 6 = 12 -> vmcnt(6) retires
//   kt+1 (read next iter). WAR: buf (kt+2)%3 last read at iter kt-1, sealed by its
//   barrier. Tail: kt=70 no stage, vmcnt(0); kt=71 free-run.

#define MFMA14(miA, miB)                                                        \
    __builtin_amdgcn_s_setprio(1);                                              \
    _Pragma("unroll")                                                           \
    for (int ni = 0; ni < 7; ++ni) {                                            \
        acc[miA][ni] = __builtin_amdgcn_mfma_f32_16x16x32_bf16(                 \
            af[miA], bf[ni], acc[miA][ni], 0, 0, 0);                            \
        acc[miB][ni] = __builtin_amdgcn_mfma_f32_16x16x32_bf16(                 \
            af[miB], bf[ni], acc[miB][ni], 0, 0, 0);                            \
    }                                                                           \
    __builtin_amdgcn_s_setprio(0);

#define RD_MAIN(abase, bbase)                                                   \
    _Pragma("unroll")                                                           \
    for (int mi = 0; mi < 2; ++mi)                                              \
        af[mi] = *(const bf16x8*)&lds[(abase) + arow + mi * 512];               \
    _Pragma("unroll")                                                           \
    for (int ni = 0; ni < 7; ++ni)                                              \
        bf[ni] = *(const bf16x8*)&lds[(bbase) + brow + ni * 512];

#define RD_TAILA(abase)                                                         \
    _Pragma("unroll")                                                           \
    for (int mi = 2; mi < 4; ++mi)                                              \
        af[mi] = *(const bf16x8*)&lds[(abase) + arow + mi * 512];

__global__ __launch_bounds__(256, 2) void gemm_conv_kernel(
    const unsigned short* __restrict__ Ap,   // [256][2304] bf16
    const unsigned short* __restrict__ Xp,   // [226][226][256] bf16
    float* __restrict__ out)                 // [256][50176]
{
    __shared__ unsigned short lds[36864];    // 72 KB: A 3x4096 | B 3x8192

    const int tid = threadIdx.x;
    const int Nb = blockIdx.x;               // 0..223
    const int Mb = blockIdx.y;               // 0..1
    const int wave = tid >> 6;               // 0..3
    const int wm = wave >> 1;                // 0..1 (M half: 64 rows)
    const int wn = wave & 1;                 // 0..1 (N half: 112 cols)
    const int lane = tid & 63;
    const int ln15 = lane & 15;
    const int quad = lane >> 4;
    const int slot8 = (quad ^ ((ln15 >> 1) & 3)) * 8;    // proven conflict-free
    const int arow = (wm * 64 + ln15) * 32 + slot8;      // + mi*512
    const int brow = (wn * 112 + ln15) * 32 + slot8;     // + ni*512 (within B buffer)

    // ---- staging sources (inverse swizzle pre-applied) ----
    const int c4 = (tid & 3) ^ ((tid >> 3) & 3);
    const unsigned short* a_src[2];
    const unsigned short* b_src[4];
#pragma unroll
    for (int j = 0; j < 2; ++j) {
        const int r = j * 64 + (tid >> 2);               // 0..127
        a_src[j] = Ap + (Mb * 128 + r) * KDIM + c4 * 8;  // + kt*32
    }
#pragma unroll
    for (int j = 0; j < 4; ++j) {
        const int r = j * 64 + (tid >> 2);               // 0..255 (224+ over-staged)
        unsigned int p = Nb * BN + r;
        unsigned int hi = p / W, wi = p - hi * W;
        b_src[j] = Xp + (hi * HP + wi) * CI + c4 * 8;    // + tap/ci offset
    }

    f32x4 acc[4][7];
#pragma unroll
    for (int mi = 0; mi < 4; ++mi)
#pragma unroll
        for (int ni = 0; ni < 7; ++ni)
            acc[mi][ni] = (f32x4){0.f, 0.f, 0.f, 0.f};

    auto stageA = [&](int kt, int buf) {
        const int dst = buf * 4096;
        const int off = kt * 32;
#pragma unroll
        for (int j = 0; j < 2; ++j)
            load_lds16(a_src[j] + off, &lds[dst + (j * 4 + wave) * 512]);
    };
    auto stageB = [&](int kt, int buf) {
        const int dst = 12288 + buf * 8192;
        const int tap = kt >> 3;                         // 0..8 (8 K-steps per tap)
        const int dh = (tap * 11) >> 5;                  // tap/3 for tap<=8
        const int dw = tap - dh * 3;
        const int off = (dh * HP + dw) * CI + (kt & 7) * 32;
#pragma unroll
        for (int j = 0; j < 4; ++j)
            load_lds16(b_src[j] + off, &lds[dst + (j * 4 + wave) * 512]);
    };

    bf16x8 af[4], bf[7];

    // ---- prologue: stage tiles 0,1 (12 loads); retire tile 0; barrier ----
    stageA(0, 0); stageB(0, 0);
    stageA(1, 1); stageB(1, 1);
    asm volatile("s_waitcnt vmcnt(6)" ::: "memory");     // tile 0 landed
    __builtin_amdgcn_s_barrier();

    int buf = 0;                                         // kt % 3
    for (int kt = 0; kt < 72; ++kt) {
        const int sbuf = (buf == 0) ? 2 : buf - 1;       // (kt+2) % 3
        const int abase = buf * 4096;
        const int bbase = 12288 + buf * 8192;
        const bool st = kt < 70;
        RD_MAIN(abase, bbase)
        if (st) stageA(kt + 2, sbuf);
        MFMA14(0, 1)
        RD_TAILA(abase)
        if (st) stageB(kt + 2, sbuf);
        MFMA14(2, 3)
        if (st) {
            asm volatile("s_waitcnt vmcnt(6)" ::: "memory");  // tile kt+1 landed
            __builtin_amdgcn_s_barrier();
        } else if (kt == 70) {
            asm volatile("s_waitcnt vmcnt(0)" ::: "memory");  // tile 71 landed
            __builtin_amdgcn_s_barrier();
        }
        buf = (buf == 2) ? 0 : buf + 1;
    }

    // ---- epilogue: C/D layout col = lane&15 (n=p), row = quad*4 + reg (m=co) ----
    const int pcol = Nb * BN + wn * 112 + ln15;
    const int corow = Mb * 128 + wm * 64 + quad * 4;
#pragma unroll
    for (int mi = 0; mi < 4; ++mi)
#pragma unroll
        for (int ni = 0; ni < 7; ++ni)
#pragma unroll
            for (int r = 0; r < 4; ++r)
                out[(corow + mi * 16 + r) * NPOS + pcol + ni * 16] = acc[mi][ni][r];
}

extern "C" void kernel_launch(void* const* d_in, const int* in_sizes, int n_in,
                              void* d_out, int out_size, void* d_ws, size_t ws_size,
                              hipStream_t stream) {
    const float* x = (const float*)d_in[0];       // [1,256,224,224]
    const float* w = (const float*)d_in[1];       // [256,256,3,3]
    float* out = (float*)d_out;                   // [256,224,224]

    unsigned short* xp = (unsigned short*)d_ws;        // 13,075,456 shorts
    unsigned short* ap = xp + XP_ELEMS;                // 589,824 shorts

    prep_kernel<<<XT_BLOCKS + WT_BLOCKS + 113, 256, 0, stream>>>(x, w, ap, xp);
    gemm_conv_kernel<<<dim3(NPOS / BN, 2), 256, 0, stream>>>(ap, xp, out);
}

// Round 15
// 153.677 us; speedup vs baseline: 1.0754x; 1.0754x over previous
//
#include <hip/hip_runtime.h>

// Conv2d 3x3 pad1 stride1, x[1,256,224,224] f32, w[256,256,3,3] f32 -> out[256,224,224] f32
// Implicit GEMM: M=256 (co), N=50176 (h*224+w), K=2304 (tap-major: k = (dh*3+dw)*256 + ci)
// R21 = R18 (session champion, 152.7us total / 72.3us gemm): BN=224 tiling, grid 224
//      (1 block/CU), 8 waves (4Mx2N), wave-tile 64x112, BK=64, 2 K-tile LDS buffers,
//      free-run kappa halves with counted vmcnt(4) ladder (never 0 in loop), proven
//      conflict-free swizzle (SQ_LDS_BANK_CONFLICT = 0). Reverted here after R19/R20
//      (cross-block anti-phase) regressed: M-split doubles B fetch (63->145MB).
//      Session ledger: lockstep(R11) 78 / swizzle-fix(R12) 71.6 / free-run(R13) 71.1 /
//      shape-32x32(R14,R15) 85,75 / issue-early(R16) 76.9 / reg-prefetch(R17) 71.3 null
//      (compiler sinks prefetch, VGPR=124 tell) / re-tile(R18) 72.3 best-total /
//      anti-phase(R20) 81. Residual ~550ns/kappa = LDS-latency+staging+join exposed at
//      in-phase 2 waves/SIMD; not removable at HIP source level (6 distinct nulls).

#define H 224
#define W 224
#define NPOS (H*W)          // 50176
#define CI 256
#define CO 256
#define KDIM 2304
#define HP 226              // padded
#define XP_ELEMS (HP*HP*CI) // 13,075,456 shorts
#define AP_ELEMS (CO*KDIM)  // 589,824 shorts
#define BN 224              // N-tile: 50176/224 = 224 blocks = 1/CU

typedef __bf16 bf16x8 __attribute__((ext_vector_type(8)));
typedef float f32x4 __attribute__((ext_vector_type(4)));
typedef unsigned short u16x4 __attribute__((ext_vector_type(4)));
typedef unsigned short u16x8 __attribute__((ext_vector_type(8)));

__device__ __forceinline__ unsigned short f2bf(float f) {
    unsigned int u = __float_as_uint(f);
    u += 0x7fff + ((u >> 16) & 1);   // round-to-nearest-even
    return (unsigned short)(u >> 16);
}

__device__ __forceinline__ void load_lds16(const unsigned short* g, unsigned short* l) {
    __builtin_amdgcn_global_load_lds(
        (const __attribute__((address_space(1))) void*)g,
        (__attribute__((address_space(3))) void*)l,
        16, 0, 0);
}

// ---- fused prep (unchanged from R8): xtrans + weight transform + border zero ----
#define XT_BLOCKS 3136      // 784 * 4
#define WT_BLOCKS 256
#define BORDER_V8 28800     // 230,400 shorts / 8
#define ROW_V8 7232         // 226*256/8
__global__ void prep_kernel(const float* __restrict__ x, const float* __restrict__ w,
                            unsigned short* __restrict__ ap, unsigned short* __restrict__ xp) {
    __shared__ unsigned short smem[64 * 68];
    const int bx = blockIdx.x;
    const int t = threadIdx.x;

    if (bx < XT_BLOCKS) {
        const unsigned int pBase = (unsigned int)(bx % 784) * 64;
        const unsigned int ciBase = (unsigned int)(bx / 784) * 64;
        {
            const int p4 = (t & 15) * 4;
            const int c0 = t >> 4;               // 0..15
#pragma unroll
            for (int i = 0; i < 4; ++i) {
                const int ci_l = c0 + i * 16;
                const f32x4 v = *(const f32x4*)&x[(ciBase + ci_l) * NPOS + pBase + p4];
                u16x4 s;
                s[0] = f2bf(v[0]); s[1] = f2bf(v[1]); s[2] = f2bf(v[2]); s[3] = f2bf(v[3]);
                *(u16x4*)&smem[ci_l * 68 + p4] = s;
            }
        }
        __syncthreads();
        {
            const int ci0 = (t & 7) * 8;
            const int pr = t >> 3;               // 0..31
#pragma unroll
            for (int j = 0; j < 2; ++j) {
                const int p_l = pr + j * 32;
                const unsigned int p = pBase + p_l;
                const unsigned int hi = p / W, wi = p - hi * W;
                u16x8 v;
#pragma unroll
                for (int k = 0; k < 8; ++k) v[k] = smem[(ci0 + k) * 68 + p_l];
                *(u16x8*)&xp[((hi + 1) * HP + (wi + 1)) * CI + ciBase + ci0] = v;
            }
        }
    } else if (bx < XT_BLOCKS + WT_BLOCKS) {
        const int co = bx - XT_BLOCKS;
        const float* wc = w + co * KDIM;
#pragma unroll
        for (int i = 0; i < 9; ++i)
            smem[i * 256 + t] = f2bf(wc[i * 256 + t]);
        __syncthreads();
        unsigned short* apc = ap + co * KDIM;
#pragma unroll
        for (int tap = 0; tap < 9; ++tap)
            apc[tap * 256 + t] = smem[t * 9 + tap];
    } else {
        const int idx = (bx - XT_BLOCKS - WT_BLOCKS) * 256 + t;
        if (idx < BORDER_V8) {
            unsigned short* p;
            if (idx < 2 * ROW_V8) {
                const int r = idx / ROW_V8;
                const int off = idx - r * ROW_V8;
                p = xp + r * (225 * HP * CI) + off * 8;
            } else {
                const int i2 = idx - 2 * ROW_V8;
                const int seg = i2 >> 5;
                const int o = i2 & 31;
                const int hp = 1 + (seg >> 1);
                const int wp = (seg & 1) * 225;
                p = xp + (hp * HP + wp) * CI + o * 8;
            }
            *(u16x8*)p = (u16x8){0, 0, 0, 0, 0, 0, 0, 0};
        }
    }
}

// ---- implicit GEMM, 256x224 tile, BK=64, 8 waves (4Mx2N), wave-tile 64x112 ----
// LDS (shorts): A[pi][kappa] = 4 regions x 8192 at [0,32768); B likewise at +32768
//   (B rows 224..255 of each region are over-staged, never read).
//   Slot s of row r holds chunk s ^ ((r&15)>>1 & 3); source pre-swizzle
//   c4 = (l&3)^((l>>3)&3); read slot quad^((ln15>>1)&3). Proven 0-conflict (R12/R13).
// Per kappa half (K=32): {read af[0..1]+bf[0..6] (9 ds); stageA(kt+1,k); 14 MFMA
//   (mi 0-1); read af[2..3] (2 ds); stageB(kt+1,k); 14 MFMA (mi 2-3); vmcnt(4); bar}.
// vmcnt ladder identical to R13 (4 loads/thread/kappa, issue order A,B per kappa):
//   kappa0-end: outstanding = kt.k1(4)+kt+1.k0(4) -> vmcnt(4) retires kt's k1.
//   kappa1-end: outstanding = kt+1's 8 -> vmcnt(4) retires kt+1's k0.
//   Tail kt=35: kappa0-end vmcnt(0), no trailing wait.

#define MFMA14(miA, miB)                                                        \
    __builtin_amdgcn_s_setprio(1);                                              \
    _Pragma("unroll")                                                           \
    for (int ni = 0; ni < 7; ++ni) {                                            \
        acc[miA][ni] = __builtin_amdgcn_mfma_f32_16x16x32_bf16(                 \
            af[miA], bf[ni], acc[miA][ni], 0, 0, 0);                            \
        acc[miB][ni] = __builtin_amdgcn_mfma_f32_16x16x32_bf16(                 \
            af[miB], bf[ni], acc[miB][ni], 0, 0, 0);                            \
    }                                                                           \
    __builtin_amdgcn_s_setprio(0);

__global__ __launch_bounds__(512, 1) void gemm_conv_kernel(
    const unsigned short* __restrict__ Ap,   // [256][2304] bf16
    const unsigned short* __restrict__ Xp,   // [226][226][256] bf16
    float* __restrict__ out)                 // [256][50176]
{
    __shared__ unsigned short lds[65536];    // 128 KB

    const int tid = threadIdx.x;
    const int Nb = blockIdx.x;               // 0..223
    const int wave = tid >> 6;               // 0..7
    const int wm = wave >> 1;                // 0..3 (M quarter: 64 rows)
    const int wn = wave & 1;                 // 0..1 (N half: 112 cols)
    const int lane = tid & 63;
    const int ln15 = lane & 15;
    const int quad = lane >> 4;
    const int slot8 = (quad ^ ((ln15 >> 1) & 3)) * 8;    // proven conflict-free
    const int arow = (wm * 64 + ln15) * 32 + slot8;      // + mi*512
    const int brow = 32768 + (wn * 112 + ln15) * 32 + slot8;  // + ni*512

    // ---- staging sources (inverse swizzle pre-applied; mapping unchanged) ----
    const int c4 = (tid & 3) ^ ((tid >> 3) & 3);
    const unsigned short* a_src[2];
    const unsigned short* b_src[2];
#pragma unroll
    for (int j = 0; j < 2; ++j) {
        const int r = j * 128 + (tid >> 2);              // 0..255
        a_src[j] = Ap + r * KDIM + c4 * 8;               // + kt*64 + kappa*32
        unsigned int p = Nb * BN + r;                    // rows 224-255: over-stage (safe)
        unsigned int hi = p / W, wi = p - hi * W;
        b_src[j] = Xp + (hi * HP + wi) * CI + c4 * 8;    // + tap/ci offset
    }

    f32x4 acc[4][7];
#pragma unroll
    for (int mi = 0; mi < 4; ++mi)
#pragma unroll
        for (int ni = 0; ni < 7; ++ni)
            acc[mi][ni] = (f32x4){0.f, 0.f, 0.f, 0.f};

    auto stageA = [&](int kt, int k) {
        const int dst = ((kt & 1) * 2 + k) * 8192;
        const int off = kt * 64 + k * 32;
#pragma unroll
        for (int j = 0; j < 2; ++j)
            load_lds16(a_src[j] + off, &lds[dst + (j * 8 + wave) * 512]);
    };
    auto stageB = [&](int kt, int k) {
        const int dst = 32768 + ((kt & 1) * 2 + k) * 8192;
        const int tap = kt >> 2;                         // 0..8
        const int dh = (tap * 11) >> 5;                  // tap/3 for tap<=8
        const int dw = tap - dh * 3;
        const int off = (dh * HP + dw) * CI + (kt & 3) * 64 + k * 32;
#pragma unroll
        for (int j = 0; j < 2; ++j)
            load_lds16(b_src[j] + off, &lds[dst + (j * 8 + wave) * 512]);
    };

    bf16x8 af[4], bf[7];

#define RD_MAIN(base)                                                           \
    _Pragma("unroll")                                                           \
    for (int mi = 0; mi < 2; ++mi)                                              \
        af[mi] = *(const bf16x8*)&lds[(base) + arow + mi * 512];                \
    _Pragma("unroll")                                                           \
    for (int ni = 0; ni < 7; ++ni)                                              \
        bf[ni] = *(const bf16x8*)&lds[(base) + brow + ni * 512];

#define RD_TAILA(base)                                                          \
    _Pragma("unroll")                                                           \
    for (int mi = 2; mi < 4; ++mi)                                              \
        af[mi] = *(const bf16x8*)&lds[(base) + arow + mi * 512];

    // ---- prologue: stage K-tile 0 (Ak0,Bk0,Ak1,Bk1 = 8 loads); keep k1 in flight ----
    stageA(0, 0); stageB(0, 0); stageA(0, 1); stageB(0, 1);
    asm volatile("s_waitcnt vmcnt(4)" ::: "memory");     // Ak0,Bk0 landed
    __builtin_amdgcn_s_barrier();

    for (int kt = 0; kt < 36; ++kt) {
        const int b0 = (kt & 1) * 16384;                 // kappa = 0 region
        const int b1 = b0 + 8192;                        // kappa = 1 region
        const bool st = kt < 35;
        // ---- kappa = 0 half: free-run ----
        RD_MAIN(b0)
        if (st) stageA(kt + 1, 0);
        MFMA14(0, 1)
        RD_TAILA(b0)
        if (st) stageB(kt + 1, 0);
        MFMA14(2, 3)
        if (st) asm volatile("s_waitcnt vmcnt(4)" ::: "memory");
        else    asm volatile("s_waitcnt vmcnt(0)" ::: "memory");
        __builtin_amdgcn_s_barrier();                    // kt's k1 landed, wave-global
        // ---- kappa = 1 half ----
        RD_MAIN(b1)
        if (st) stageA(kt + 1, 1);
        MFMA14(0, 1)
        RD_TAILA(b1)
        if (st) stageB(kt + 1, 1);
        MFMA14(2, 3)
        if (st) {
            asm volatile("s_waitcnt vmcnt(4)" ::: "memory");
            __builtin_amdgcn_s_barrier();                // kt+1's k0 landed; seals reads
        }
    }

    // ---- epilogue: C/D layout col = lane&15 (n=p), row = quad*4 + reg (m=co) ----
    const int pcol = Nb * BN + wn * 112 + ln15;
    const int corow = wm * 64 + quad * 4;
#pragma unroll
    for (int mi = 0; mi < 4; ++mi)
#pragma unroll
        for (int ni = 0; ni < 7; ++ni)
#pragma unroll
            for (int r = 0; r < 4; ++r)
                out[(corow + mi * 16 + r) * NPOS + pcol + ni * 16] = acc[mi][ni][r];
}

extern "C" void kernel_launch(void* const* d_in, const int* in_sizes, int n_in,
                              void* d_out, int out_size, void* d_ws, size_t ws_size,
                              hipStream_t stream) {
    const float* x = (const float*)d_in[0];       // [1,256,224,224]
    const float* w = (const float*)d_in[1];       // [256,256,3,3]
    float* out = (float*)d_out;                   // [256,224,224]

    unsigned short* xp = (unsigned short*)d_ws;        // 13,075,456 shorts
    unsigned short* ap = xp + XP_ELEMS;                // 589,824 shorts

    prep_kernel<<<XT_BLOCKS + WT_BLOCKS + 113, 256, 0, stream>>>(x, w, ap, xp);
    gemm_conv_kernel<<<dim3(NPOS / BN), 512, 0, stream>>>(ap, xp, out);
}